// Round 12
// baseline (344.460 us; speedup 1.0000x reference)
//
#include <hip/hip_runtime.h>
#include <hip/hip_bf16.h>

#define NAGENT 64
#define HID    128
#define TOBS   8
#define PREDL  12
#define NTHR   1024
#define XH     136    // sh_X / sh_H row pitch (ushort): 272B, 16B-aligned for b128
#define PP     264    // sh_P row pitch: 528B, 16B-aligned
#define SPP    268    // sh_S row pitch: 536B (8B-aligned rows for b64 reads)

typedef __attribute__((ext_vector_type(8))) short bf16x8;
typedef __attribute__((ext_vector_type(4))) short bf16x4;
typedef __attribute__((ext_vector_type(4))) float f32x4;
typedef __attribute__((ext_vector_type(2))) unsigned int u32x2;

__device__ __forceinline__ unsigned short f2bf(float f) {
    __hip_bfloat16 h = __float2bfloat16(f);           // RNE; compiler lowers to HW cvt
    return __builtin_bit_cast(unsigned short, h);
}
__device__ __forceinline__ float bf2f(unsigned short u) {
    return __uint_as_float(((unsigned int)u) << 16);
}
// sigm/tanh on exp2 (v_exp_f32 is 2^x): no clamp needed, inf/0 saturate correctly.
__device__ __forceinline__ float sigmf(float x) {
    return __builtin_amdgcn_rcpf(1.0f + __builtin_amdgcn_exp2f(x * -1.442695041f));
}
__device__ __forceinline__ float tanhf_fast(float x) {
    const float s = __builtin_amdgcn_rcpf(1.0f + __builtin_amdgcn_exp2f(x * -2.885390082f));
    return __builtin_fmaf(2.0f, s, -1.0f);
}
__device__ __forceinline__ float sel4(float a0, float a1, float a2, float a3, int k) {
    float lo = (k & 1) ? a1 : a0;
    float hi = (k & 1) ? a3 : a2;
    return (k & 2) ? hi : lo;
}

// ---------------- prep: pack weights into bf16 MFMA B-fragment layouts ----------------
// wd (D): B[k][n], k 0..255 ([et|at|h]), n 0..511 INTERLEAVED n = d*4+g (1x traffic).
// wb (B): B[k][r], k 0..127 (h), r = e*4+g (16 nt x 4 kt)
// wp (proj): B[k][n], k 0..127 (h), n 0..15 (cols >=5 zero); hi (frags 0..3) + lo (4..7)
__global__ void prep_weights(const float* __restrict__ Wih, const float* __restrict__ Whh,
                             const float* __restrict__ socW, const float* __restrict__ predW,
                             unsigned short* __restrict__ wd, unsigned short* __restrict__ wb,
                             unsigned short* __restrict__ wp) {
    int idx = blockIdx.x * 256 + threadIdx.x;
    if (idx < 131072) {
        int e = idx & 7, l = (idx >> 3) & 63, t = idx >> 9;   // t = nt*8+kt
        int kt = t & 7, nt = t >> 3;
        int k = kt * 32 + ((l >> 4) << 3) + e;
        int n = nt * 16 + (l & 15);
        int d = n >> 2, g = n & 3;                            // n = d*4+g
        int row = g * 128 + d;
        float v = (k < 128) ? Wih[row * 128 + k] : Whh[row * 128 + (k - 128)];
        wd[idx] = f2bf(v);
    } else if (idx < 163840) {
        int i2 = idx - 131072;
        int e = i2 & 7, l = (i2 >> 3) & 63, t = i2 >> 9;      // t = nt*4+kt
        int kt = t & 3, nt = t >> 2;
        int k = kt * 32 + ((l >> 4) << 3) + e;
        int r = nt * 16 + (l & 15);
        int eo = r >> 2, g = r & 3;
        wb[i2] = f2bf(socW[eo * 512 + g * 128 + k]);
    } else if (idx < 167936) {
        int i3 = idx - 163840;
        int e = i3 & 7, l = (i3 >> 3) & 63, f = i3 >> 9;      // f = half*4+kt
        int kt = f & 3, half = f >> 2;
        int k = kt * 32 + ((l >> 4) << 3) + e;
        int n = l & 15;
        float v = (n < 5) ? predW[n * 128 + k] : 0.0f;
        unsigned short hi = f2bf(v);
        wp[i3] = half ? f2bf(v - bf2f(hi)) : hi;
    }
}

// ---------------- main: one block per 64-agent scene, 16 waves ----------------
// R12 = R11 + (a) exp2 activations (b) HW bf16 cvt (c) 64-bit-shift one-hot
//           + (d) D split across the R2 barrier: h-half (kt 4..7, needs only h)
//             runs in R2 with C2; x-half (kt 0..3, needs et|at) + pointwise in R3.
__global__ __launch_bounds__(NTHR) void social_lstm_mfma(
    const float* __restrict__ past_traj, const float* __restrict__ past_traj_rel,
    const int* __restrict__ ts_mask, const int* __restrict__ scene_in,
    const float* __restrict__ pos_W, const float* __restrict__ pos_b,
    const float* __restrict__ soc_b,
    const float* __restrict__ bih, const float* __restrict__ bhh,
    const float* __restrict__ h0, const float* __restrict__ c0,
    const float* __restrict__ pred_b,
    const unsigned short* __restrict__ wd, const unsigned short* __restrict__ wb,
    const unsigned short* __restrict__ wp,
    float* __restrict__ out)
{
    __shared__ __align__(16) unsigned short sh_X[NAGENT][XH];     // 0..63 et | 64..127 at
    __shared__ __align__(16) unsigned short sh_H[2][NAGENT][XH];  // h double buffer
    __shared__ __align__(16) unsigned short sh_P[NAGENT][PP];     // P[i][j*4+g] bf16 0/1
    __shared__ __align__(16) unsigned short sh_S[NAGENT][SPP];    // S[j][r], r = e*4+g
    __shared__ float sh_px[2][NAGENT], sh_py[2][NAGENT];
    __shared__ float sh_rx[2][NAGENT], sh_ry[2][NAGENT];
    __shared__ __align__(16) int sh_act[2][NAGENT];
    __shared__ int sh_scene[NAGENT];

    const int tid  = threadIdx.x;
    const int lane = tid & 63;
    const int wv   = __builtin_amdgcn_readfirstlane(tid >> 6);  // 0..15
    const int gbase = blockIdx.x * NAGENT;
    const int c16 = lane & 15;   // tile col
    const int q4  = lane >> 4;   // quad
    const int go  = c16 & 3;     // owned gate (D pointwise)
    const int dq  = c16 >> 2;    // dim-within-ntile

    // per-wave geometry: phase D N-tiles 2wv, 2wv+1 (interleaved n = d*4+g)
    float bs[2], c_st[4][2], h_rg[4][2];
    int dimv[2];
    #pragma unroll
    for (int s = 0; s < 2; ++s) {
        const int n = (2 * wv + s) * 16 + c16;
        const int d = n >> 2, g = n & 3;
        bs[s] = bih[g * 128 + d] + bhh[g * 128 + d];
        dimv[s] = (2 * wv + s) * 4 + dq;
        const float hz = h0[dimv[s]], cz = c0[dimv[s]];
        #pragma unroll
        for (int mj = 0; mj < 4; ++mj) { c_st[mj][s] = cz; h_rg[mj][s] = hz; }
    }
    for (int p = tid; p < NAGENT * HID; p += NTHR) {
        int a = p >> 7, d = p & 127;
        sh_H[0][a][d] = f2bf(h0[d]);
    }
    if (tid < NAGENT) {
        const int ig = gbase + tid;
        sh_scene[tid] = scene_in[ig];
        sh_px[0][tid] = past_traj[(ig * TOBS + 0) * 2 + 0];
        sh_py[0][tid] = past_traj[(ig * TOBS + 0) * 2 + 1];
        sh_rx[0][tid] = past_traj_rel[(ig * TOBS + 0) * 2 + 0];
        sh_ry[0][tid] = past_traj_rel[(ig * TOBS + 0) * 2 + 1];
        sh_act[0][tid] = (ts_mask[ig * TOBS + 0] == 1) ? 1 : 0;
    }
    __syncthreads();

    const bf16x8* wdp = (const bf16x8*)wd + (2 * wv * 8) * 64 + lane;  // +kt*64, +512 nt+1
    const bf16x8* wbv = (const bf16x8*)wb;

    for (int step = 0; step < TOBS + PREDL; ++step) {
        const int pb = step & 1;                    // pos/rel parity
        const int hb = step & 1;                    // h parity
        const int ab = (step < TOBS) ? pb : 1;      // act parity (pred: frozen at step 7)

        if (step >= TOBS) {
            // ---- slot 0 (pred): proj on waves 0..3  ||  B (S = h @ wb) on waves 4..15 ----
            if (wv < 4) {
                const bf16x8* wpv = (const bf16x8*)wp;
                f32x4 pa = (f32x4){0.f, 0.f, 0.f, 0.f};
                #pragma unroll
                for (int kt = 0; kt < 4; ++kt) {
                    const bf16x8 a = *(const bf16x8*)&sh_H[hb][wv * 16 + c16][kt * 32 + q4 * 8];
                    pa = __builtin_amdgcn_mfma_f32_16x16x32_bf16(a, wpv[kt * 64 + lane], pa, 0, 0, 0);
                    pa = __builtin_amdgcn_mfma_f32_16x16x32_bf16(a, wpv[(4 + kt) * 64 + lane], pa, 0, 0, 0);
                }
                if (c16 < 5) {
                    const float pbias = pred_b[c16];
                    const int p = step - TOBS;
                    const int pprev = (step - 1) & 1;
                    #pragma unroll
                    for (int rr = 0; rr < 4; ++rr) {
                        const int a = wv * 16 + q4 * 4 + rr;
                        const float o = pa[rr] + pbias;
                        const float m = sh_act[1][a] ? 1.0f : 0.0f;
                        const int ig = gbase + a;
                        out[(ig * PREDL + p) * 5 + c16] = m * o;
                        if (c16 == 0) {
                            const float px = sh_px[pprev][a] + o;
                            sh_px[pb][a] = px; sh_rx[pb][a] = o;
                            out[61440 + (ig * PREDL + p) * 2 + 0] = m * px;
                        }
                        if (c16 == 1) {
                            const float py = sh_py[pprev][a] + o;
                            sh_py[pb][a] = py; sh_ry[pb][a] = o;
                            out[61440 + (ig * PREDL + p) * 2 + 1] = m * py;
                        }
                    }
                }
            } else {
                // waves 4..15 cover 16 r-tiles: tile wv-4, and wv<8 also tile wv+8
                #pragma unroll
                for (int pass = 0; pass < 2; ++pass) {
                    const int tt = (pass == 0) ? (wv - 4) : (wv + 8);
                    if (pass == 1 && wv >= 8) break;
                    f32x4 acc2[4];
                    #pragma unroll
                    for (int mj = 0; mj < 4; ++mj) acc2[mj] = (f32x4){0.f, 0.f, 0.f, 0.f};
                    #pragma unroll
                    for (int kt = 0; kt < 4; ++kt) {
                        const bf16x8 b = wbv[(tt * 4 + kt) * 64 + lane];
                        #pragma unroll
                        for (int mj = 0; mj < 4; ++mj) {
                            const bf16x8 a = *(const bf16x8*)&sh_H[hb][mj * 16 + c16][kt * 32 + q4 * 8];
                            acc2[mj] = __builtin_amdgcn_mfma_f32_16x16x32_bf16(a, b, acc2[mj], 0, 0, 0);
                        }
                    }
                    const int rcol = tt * 16 + c16;
                    #pragma unroll
                    for (int mj = 0; mj < 4; ++mj)
                        #pragma unroll
                        for (int rr = 0; rr < 4; ++rr)
                            sh_S[mj * 16 + q4 * 4 + rr][rcol] = f2bf(acc2[mj][rr]);
                }
            }
            __syncthreads();
        }

        // ==== R1: Phase A (P one-hot), et, and (obs only) Phase B ====
        #pragma unroll
        for (int it = 0; it < 4; ++it) {
            const int p = it * NTHR + tid;
            const int i = p >> 6, j = p & 63;     // i wave-uniform, j = lane
            const float dx = sh_px[pb][j] - sh_px[pb][i];
            const float dy = sh_py[pb][j] - sh_py[pb][i];
            const bool within = (dx < 0.99f) & (dx > -0.99f) & (dy < 0.99f) & (dy > -0.99f);
            const bool pair = within && (i != j) && (sh_scene[i] == sh_scene[j])
                              && sh_act[ab][i] && sh_act[ab][j];
            const int gid = ((dx >= 0.f) ? 2 : 0) + ((dy >= 0.f) ? 1 : 0);
            const unsigned long long w = pair ? (0x3f80ull << (gid << 4)) : 0ull;
            u32x2 wv2; wv2[0] = (unsigned int)w; wv2[1] = (unsigned int)(w >> 32);
            *(u32x2*)&sh_P[i][j * 4] = wv2;
        }
        {   // et: wave wv -> embed dims wv*4.., lane = agent
            const float rx = sh_rx[pb][lane], ry = sh_ry[pb][lane];
            const int e0 = wv * 4;
            #pragma unroll
            for (int u = 0; u < 4; ++u) {
                const int e = e0 + u;
                sh_X[lane][e] = f2bf(fmaxf(pos_b[e] + rx * pos_W[e * 2] + ry * pos_W[e * 2 + 1], 0.f));
            }
        }
        if (step < TOBS) {   // Phase B (obs): wave = r-tile wv; row-natural store
            f32x4 acc2[4];
            #pragma unroll
            for (int mj = 0; mj < 4; ++mj) acc2[mj] = (f32x4){0.f, 0.f, 0.f, 0.f};
            #pragma unroll
            for (int kt = 0; kt < 4; ++kt) {
                const bf16x8 b = wbv[(wv * 4 + kt) * 64 + lane];
                #pragma unroll
                for (int mj = 0; mj < 4; ++mj) {
                    const bf16x8 a = *(const bf16x8*)&sh_H[hb][mj * 16 + c16][kt * 32 + q4 * 8];
                    acc2[mj] = __builtin_amdgcn_mfma_f32_16x16x32_bf16(a, b, acc2[mj], 0, 0, 0);
                }
            }
            const int rcol = wv * 16 + c16;
            #pragma unroll
            for (int mj = 0; mj < 4; ++mj)
                #pragma unroll
                for (int rr = 0; rr < 4; ++rr)
                    sh_S[mj * 16 + q4 * 4 + rr][rcol] = f2bf(acc2[mj][rr]);
        }
        __syncthreads();

        // ==== R2: C2 (at = relu(P@S+soc_b)) + D h-half (kt 4..7, A = h) ====
        f32x4 acc[4][2];   // D accumulators, live across the barrier into R3
        #pragma unroll
        for (int mj = 0; mj < 4; ++mj) {
            acc[mj][0] = (f32x4){0.f, 0.f, 0.f, 0.f};
            acc[mj][1] = (f32x4){0.f, 0.f, 0.f, 0.f};
        }
        {
            const int mt = wv & 3, nt = wv >> 2;
            const int cb = 4 * (nt * 16 + c16);
            f32x4 cac = (f32x4){0.f, 0.f, 0.f, 0.f};
            #pragma unroll
            for (int kt = 0; kt < 8; ++kt) {
                const bf16x8 a = *(const bf16x8*)&sh_P[mt * 16 + c16][kt * 32 + q4 * 8];
                const int j0 = kt * 8 + q4 * 2;
                const bf16x4 lo = *(const bf16x4*)&sh_S[j0][cb];
                const bf16x4 hi = *(const bf16x4*)&sh_S[j0 + 1][cb];
                const bf16x8 b = __builtin_shufflevector(lo, hi, 0, 1, 2, 3, 4, 5, 6, 7);
                cac = __builtin_amdgcn_mfma_f32_16x16x32_bf16(a, b, cac, 0, 0, 0);
            }
            const int e = nt * 16 + c16;
            const float sb = soc_b[e];
            #pragma unroll
            for (int rr = 0; rr < 4; ++rr)
                sh_X[mt * 16 + q4 * 4 + rr][64 + e] = f2bf(fmaxf(cac[rr] + sb, 0.f));
        }
        #pragma unroll
        for (int kt = 4; kt < 8; ++kt) {
            const bf16x8 b0 = wdp[kt * 64];
            const bf16x8 b1 = wdp[kt * 64 + 512];
            #pragma unroll
            for (int mj = 0; mj < 4; ++mj) {
                const bf16x8 a = *(const bf16x8*)&sh_H[hb][mj * 16 + c16][(kt - 4) * 32 + q4 * 8];
                acc[mj][0] = __builtin_amdgcn_mfma_f32_16x16x32_bf16(a, b0, acc[mj][0], 0, 0, 0);
                acc[mj][1] = __builtin_amdgcn_mfma_f32_16x16x32_bf16(a, b1, acc[mj][1], 0, 0, 0);
            }
        }
        __syncthreads();

        // ==== R3: D x-half (kt 0..3, A = et|at) + shfl pointwise; h' via h_rg ====
        {
            #pragma unroll
            for (int kt = 0; kt < 4; ++kt) {
                const bf16x8 b0 = wdp[kt * 64];
                const bf16x8 b1 = wdp[kt * 64 + 512];
                #pragma unroll
                for (int mj = 0; mj < 4; ++mj) {
                    const bf16x8 a = *(const bf16x8*)&sh_X[mj * 16 + c16][kt * 32 + q4 * 8];
                    acc[mj][0] = __builtin_amdgcn_mfma_f32_16x16x32_bf16(a, b0, acc[mj][0], 0, 0, 0);
                    acc[mj][1] = __builtin_amdgcn_mfma_f32_16x16x32_bf16(a, b1, acc[mj][1], 0, 0, 0);
                }
            }
            // pointwise LSTM: 4-lane gate exchange; hold in h_rg, write h' to sh_H[hb^1]
            #pragma unroll
            for (int mj = 0; mj < 4; ++mj) {
                const int a = mj * 16 + q4 * 4 + go;
                const bool act = sh_act[ab][a] != 0;
                #pragma unroll
                for (int s = 0; s < 2; ++s) {
                    const float z0 = acc[mj][s][0] + bs[s];
                    const float z1 = acc[mj][s][1] + bs[s];
                    const float z2 = acc[mj][s][2] + bs[s];
                    const float z3 = acc[mj][s][3] + bs[s];
                    const float s0 = sel4(z0, z1, z2, z3, go);
                    const float s1 = sel4(z0, z1, z2, z3, go ^ 1);
                    const float s2 = sel4(z0, z1, z2, z3, go ^ 2);
                    const float s3 = sel4(z0, z1, z2, z3, go ^ 3);
                    const float t1 = __shfl_xor(s1, 1, 64);
                    const float t2 = __shfl_xor(s2, 2, 64);
                    const float t3 = __shfl_xor(s3, 3, 64);
                    const float zi = sel4(s0, t1, t2, t3, go);
                    const float zf = sel4(s0, t1, t2, t3, go ^ 1);
                    const float zg = sel4(s0, t1, t2, t3, go ^ 2);
                    const float zo = sel4(s0, t1, t2, t3, go ^ 3);
                    const float cold = c_st[mj][s];
                    const float cn = sigmf(zf) * cold + sigmf(zi) * tanhf_fast(zg);
                    const float hn = sigmf(zo) * tanhf_fast(cn);
                    c_st[mj][s] = act ? cn : cold;
                    h_rg[mj][s] = act ? hn : h_rg[mj][s];
                    sh_H[hb ^ 1][a][dimv[s]] = f2bf(h_rg[mj][s]);
                }
            }
        }
        // obs prefetch for step+1 into the idle parity
        if (step + 1 < TOBS && tid < NAGENT) {
            const int ig = gbase + tid;
            const int np = (step + 1) & 1;
            sh_px[np][tid] = past_traj[(ig * TOBS + step + 1) * 2 + 0];
            sh_py[np][tid] = past_traj[(ig * TOBS + step + 1) * 2 + 1];
            sh_rx[np][tid] = past_traj_rel[(ig * TOBS + step + 1) * 2 + 0];
            sh_ry[np][tid] = past_traj_rel[(ig * TOBS + step + 1) * 2 + 1];
            sh_act[np][tid] = (ts_mask[ig * TOBS + step + 1] == 1) ? 1 : 0;
        }
        __syncthreads();   // end of step
    }
}

extern "C" void kernel_launch(void* const* d_in, const int* in_sizes, int n_in,
                              void* d_out, int out_size, void* d_ws, size_t ws_size,
                              hipStream_t stream) {
    (void)in_sizes; (void)n_in; (void)out_size; (void)ws_size;
    unsigned short* wd = (unsigned short*)d_ws;            // 131072 ushorts
    unsigned short* wb = wd + 131072;                      //  32768 ushorts
    unsigned short* wp = wb + 32768;                       //   4096 ushorts
    prep_weights<<<656, 256, 0, stream>>>(
        (const float*)d_in[9], (const float*)d_in[10],
        (const float*)d_in[7], (const float*)d_in[15], wd, wb, wp);
    social_lstm_mfma<<<16, NTHR, 0, stream>>>(
        (const float*)d_in[0],   // past_traj
        (const float*)d_in[1],   // past_traj_rel
        (const int*)  d_in[2],   // ts mask
        (const int*)  d_in[4],   // same_scene_mask
        (const float*)d_in[5],   // pos_W
        (const float*)d_in[6],   // pos_b
        (const float*)d_in[8],   // soc_b
        (const float*)d_in[11],  // bih
        (const float*)d_in[12],  // bhh
        (const float*)d_in[13],  // h0
        (const float*)d_in[14],  // c0
        (const float*)d_in[16],  // pred_b
        wd, wb, wp,
        (float*)d_out);
}

// Round 13
// 287.388 us; speedup vs baseline: 1.1986x; 1.1986x over previous
//
#include <hip/hip_runtime.h>
#include <hip/hip_bf16.h>

#define NAGENT 64
#define HID    128
#define TOBS   8
#define PREDL  12
#define NTHR   1024
#define XH     136    // sh_X / sh_H row pitch (ushort): 272B, 16B-aligned for b128
#define PP     264    // sh_P row pitch: 528B, 16B-aligned
#define SPP    268    // sh_S row pitch: 536B (8B-aligned rows for b64 reads)

typedef __attribute__((ext_vector_type(8))) short bf16x8;
typedef __attribute__((ext_vector_type(4))) short bf16x4;
typedef __attribute__((ext_vector_type(4))) float f32x4;
typedef __attribute__((ext_vector_type(2))) unsigned int u32x2;

__device__ __forceinline__ unsigned short f2bf(float f) {
    __hip_bfloat16 h = __float2bfloat16(f);           // RNE; HW cvt
    return __builtin_bit_cast(unsigned short, h);
}
__device__ __forceinline__ float bf2f(unsigned short u) {
    return __uint_as_float(((unsigned int)u) << 16);
}
// sigm/tanh on exp2 (v_exp_f32 is 2^x): no clamp needed, inf/0 saturate correctly.
__device__ __forceinline__ float sigmf(float x) {
    return __builtin_amdgcn_rcpf(1.0f + __builtin_amdgcn_exp2f(x * -1.442695041f));
}
__device__ __forceinline__ float tanhf_fast(float x) {
    const float s = __builtin_amdgcn_rcpf(1.0f + __builtin_amdgcn_exp2f(x * -2.885390082f));
    return __builtin_fmaf(2.0f, s, -1.0f);
}
__device__ __forceinline__ float sel4(float a0, float a1, float a2, float a3, int k) {
    float lo = (k & 1) ? a1 : a0;
    float hi = (k & 1) ? a3 : a2;
    return (k & 2) ? hi : lo;
}

// ---------------- prep: pack weights into bf16 MFMA B-fragment layouts ----------------
// wd (D): B[k][n], k 0..255 ([et|at|h]), n 0..511 INTERLEAVED n = d*4+g (1x traffic).
// wb (B): B[k][r], k 0..127 (h), r = e*4+g (16 nt x 4 kt)
// wp (proj): B[k][n], k 0..127 (h), n 0..15 (cols >=5 zero); hi (frags 0..3) + lo (4..7)
__global__ void prep_weights(const float* __restrict__ Wih, const float* __restrict__ Whh,
                             const float* __restrict__ socW, const float* __restrict__ predW,
                             unsigned short* __restrict__ wd, unsigned short* __restrict__ wb,
                             unsigned short* __restrict__ wp) {
    int idx = blockIdx.x * 256 + threadIdx.x;
    if (idx < 131072) {
        int e = idx & 7, l = (idx >> 3) & 63, t = idx >> 9;   // t = nt*8+kt
        int kt = t & 7, nt = t >> 3;
        int k = kt * 32 + ((l >> 4) << 3) + e;
        int n = nt * 16 + (l & 15);
        int d = n >> 2, g = n & 3;                            // n = d*4+g
        int row = g * 128 + d;
        float v = (k < 128) ? Wih[row * 128 + k] : Whh[row * 128 + (k - 128)];
        wd[idx] = f2bf(v);
    } else if (idx < 163840) {
        int i2 = idx - 131072;
        int e = i2 & 7, l = (i2 >> 3) & 63, t = i2 >> 9;      // t = nt*4+kt
        int kt = t & 3, nt = t >> 2;
        int k = kt * 32 + ((l >> 4) << 3) + e;
        int r = nt * 16 + (l & 15);
        int eo = r >> 2, g = r & 3;
        wb[i2] = f2bf(socW[eo * 512 + g * 128 + k]);
    } else if (idx < 167936) {
        int i3 = idx - 163840;
        int e = i3 & 7, l = (i3 >> 3) & 63, f = i3 >> 9;      // f = half*4+kt
        int kt = f & 3, half = f >> 2;
        int k = kt * 32 + ((l >> 4) << 3) + e;
        int n = l & 15;
        float v = (n < 5) ? predW[n * 128 + k] : 0.0f;
        unsigned short hi = f2bf(v);
        wp[i3] = half ? f2bf(v - bf2f(hi)) : hi;
    }
}

// ---------------- main: one block per 64-agent scene, 16 waves ----------------
// R13 = R11 structure EXACTLY (D fully in R3; nothing sizable lives across a barrier --
// the 64-VGPR law, violated by R12's D-split: WRITE_SIZE 336->6256KB spill) + the three
// cheap VALU cuts from R12: exp2 activations, HW bf16 cvt, 64-bit-shift one-hot.
__global__ __launch_bounds__(NTHR) void social_lstm_mfma(
    const float* __restrict__ past_traj, const float* __restrict__ past_traj_rel,
    const int* __restrict__ ts_mask, const int* __restrict__ scene_in,
    const float* __restrict__ pos_W, const float* __restrict__ pos_b,
    const float* __restrict__ soc_b,
    const float* __restrict__ bih, const float* __restrict__ bhh,
    const float* __restrict__ h0, const float* __restrict__ c0,
    const float* __restrict__ pred_b,
    const unsigned short* __restrict__ wd, const unsigned short* __restrict__ wb,
    const unsigned short* __restrict__ wp,
    float* __restrict__ out)
{
    __shared__ __align__(16) unsigned short sh_X[NAGENT][XH];     // 0..63 et | 64..127 at
    __shared__ __align__(16) unsigned short sh_H[2][NAGENT][XH];  // h double buffer
    __shared__ __align__(16) unsigned short sh_P[NAGENT][PP];     // P[i][j*4+g] bf16 0/1
    __shared__ __align__(16) unsigned short sh_S[NAGENT][SPP];    // S[j][r], r = e*4+g
    __shared__ float sh_px[2][NAGENT], sh_py[2][NAGENT];
    __shared__ float sh_rx[2][NAGENT], sh_ry[2][NAGENT];
    __shared__ __align__(16) int sh_act[2][NAGENT];
    __shared__ int sh_scene[NAGENT];

    const int tid  = threadIdx.x;
    const int lane = tid & 63;
    const int wv   = __builtin_amdgcn_readfirstlane(tid >> 6);  // 0..15
    const int gbase = blockIdx.x * NAGENT;
    const int c16 = lane & 15;   // tile col
    const int q4  = lane >> 4;   // quad
    const int go  = c16 & 3;     // owned gate (D pointwise)
    const int dq  = c16 >> 2;    // dim-within-ntile

    // per-wave geometry: phase D N-tiles 2wv, 2wv+1 (interleaved n = d*4+g)
    float bs[2], c_st[4][2], h_rg[4][2];
    int dimv[2];
    #pragma unroll
    for (int s = 0; s < 2; ++s) {
        const int n = (2 * wv + s) * 16 + c16;
        const int d = n >> 2, g = n & 3;
        bs[s] = bih[g * 128 + d] + bhh[g * 128 + d];
        dimv[s] = (2 * wv + s) * 4 + dq;
        const float hz = h0[dimv[s]], cz = c0[dimv[s]];
        #pragma unroll
        for (int mj = 0; mj < 4; ++mj) { c_st[mj][s] = cz; h_rg[mj][s] = hz; }
    }
    for (int p = tid; p < NAGENT * HID; p += NTHR) {
        int a = p >> 7, d = p & 127;
        sh_H[0][a][d] = f2bf(h0[d]);
    }
    if (tid < NAGENT) {
        const int ig = gbase + tid;
        sh_scene[tid] = scene_in[ig];
        sh_px[0][tid] = past_traj[(ig * TOBS + 0) * 2 + 0];
        sh_py[0][tid] = past_traj[(ig * TOBS + 0) * 2 + 1];
        sh_rx[0][tid] = past_traj_rel[(ig * TOBS + 0) * 2 + 0];
        sh_ry[0][tid] = past_traj_rel[(ig * TOBS + 0) * 2 + 1];
        sh_act[0][tid] = (ts_mask[ig * TOBS + 0] == 1) ? 1 : 0;
    }
    __syncthreads();

    const bf16x8* wdp = (const bf16x8*)wd + (2 * wv * 8) * 64 + lane;  // +kt*64, +512 nt+1
    const bf16x8* wbv = (const bf16x8*)wb;

    for (int step = 0; step < TOBS + PREDL; ++step) {
        const int pb = step & 1;                    // pos/rel parity
        const int hb = step & 1;                    // h parity
        const int ab = (step < TOBS) ? pb : 1;      // act parity (pred: frozen at step 7)

        if (step >= TOBS) {
            // ---- slot 0 (pred): proj on waves 0..3  ||  B (S = h @ wb) on waves 4..15 ----
            if (wv < 4) {
                const bf16x8* wpv = (const bf16x8*)wp;
                f32x4 pa = (f32x4){0.f, 0.f, 0.f, 0.f};
                #pragma unroll
                for (int kt = 0; kt < 4; ++kt) {
                    const bf16x8 a = *(const bf16x8*)&sh_H[hb][wv * 16 + c16][kt * 32 + q4 * 8];
                    pa = __builtin_amdgcn_mfma_f32_16x16x32_bf16(a, wpv[kt * 64 + lane], pa, 0, 0, 0);
                    pa = __builtin_amdgcn_mfma_f32_16x16x32_bf16(a, wpv[(4 + kt) * 64 + lane], pa, 0, 0, 0);
                }
                if (c16 < 5) {
                    const float pbias = pred_b[c16];
                    const int p = step - TOBS;
                    const int pprev = (step - 1) & 1;
                    #pragma unroll
                    for (int rr = 0; rr < 4; ++rr) {
                        const int a = wv * 16 + q4 * 4 + rr;
                        const float o = pa[rr] + pbias;
                        const float m = sh_act[1][a] ? 1.0f : 0.0f;
                        const int ig = gbase + a;
                        out[(ig * PREDL + p) * 5 + c16] = m * o;
                        if (c16 == 0) {
                            const float px = sh_px[pprev][a] + o;
                            sh_px[pb][a] = px; sh_rx[pb][a] = o;
                            out[61440 + (ig * PREDL + p) * 2 + 0] = m * px;
                        }
                        if (c16 == 1) {
                            const float py = sh_py[pprev][a] + o;
                            sh_py[pb][a] = py; sh_ry[pb][a] = o;
                            out[61440 + (ig * PREDL + p) * 2 + 1] = m * py;
                        }
                    }
                }
            } else {
                // waves 4..15 cover 16 r-tiles: tile wv-4, and wv<8 also tile wv+8
                #pragma unroll
                for (int pass = 0; pass < 2; ++pass) {
                    const int tt = (pass == 0) ? (wv - 4) : (wv + 8);
                    if (pass == 1 && wv >= 8) break;
                    f32x4 acc2[4];
                    #pragma unroll
                    for (int mj = 0; mj < 4; ++mj) acc2[mj] = (f32x4){0.f, 0.f, 0.f, 0.f};
                    #pragma unroll
                    for (int kt = 0; kt < 4; ++kt) {
                        const bf16x8 b = wbv[(tt * 4 + kt) * 64 + lane];
                        #pragma unroll
                        for (int mj = 0; mj < 4; ++mj) {
                            const bf16x8 a = *(const bf16x8*)&sh_H[hb][mj * 16 + c16][kt * 32 + q4 * 8];
                            acc2[mj] = __builtin_amdgcn_mfma_f32_16x16x32_bf16(a, b, acc2[mj], 0, 0, 0);
                        }
                    }
                    const int rcol = tt * 16 + c16;
                    #pragma unroll
                    for (int mj = 0; mj < 4; ++mj)
                        #pragma unroll
                        for (int rr = 0; rr < 4; ++rr)
                            sh_S[mj * 16 + q4 * 4 + rr][rcol] = f2bf(acc2[mj][rr]);
                }
            }
            __syncthreads();
        }

        // ==== R1: Phase A (P one-hot), et, and (obs only) Phase B ====
        #pragma unroll
        for (int it = 0; it < 4; ++it) {
            const int p = it * NTHR + tid;
            const int i = p >> 6, j = p & 63;     // i wave-uniform, j = lane
            const float dx = sh_px[pb][j] - sh_px[pb][i];
            const float dy = sh_py[pb][j] - sh_py[pb][i];
            const bool within = (dx < 0.99f) & (dx > -0.99f) & (dy < 0.99f) & (dy > -0.99f);
            const bool pair = within && (i != j) && (sh_scene[i] == sh_scene[j])
                              && sh_act[ab][i] && sh_act[ab][j];
            const int gid = ((dx >= 0.f) ? 2 : 0) + ((dy >= 0.f) ? 1 : 0);
            const unsigned long long w = pair ? (0x3f80ull << (gid << 4)) : 0ull;
            u32x2 wv2; wv2[0] = (unsigned int)w; wv2[1] = (unsigned int)(w >> 32);
            *(u32x2*)&sh_P[i][j * 4] = wv2;
        }
        {   // et: wave wv -> embed dims wv*4.., lane = agent
            const float rx = sh_rx[pb][lane], ry = sh_ry[pb][lane];
            const int e0 = wv * 4;
            #pragma unroll
            for (int u = 0; u < 4; ++u) {
                const int e = e0 + u;
                sh_X[lane][e] = f2bf(fmaxf(pos_b[e] + rx * pos_W[e * 2] + ry * pos_W[e * 2 + 1], 0.f));
            }
        }
        if (step < TOBS) {   // Phase B (obs): wave = r-tile wv; row-natural store
            f32x4 acc2[4];
            #pragma unroll
            for (int mj = 0; mj < 4; ++mj) acc2[mj] = (f32x4){0.f, 0.f, 0.f, 0.f};
            #pragma unroll
            for (int kt = 0; kt < 4; ++kt) {
                const bf16x8 b = wbv[(wv * 4 + kt) * 64 + lane];
                #pragma unroll
                for (int mj = 0; mj < 4; ++mj) {
                    const bf16x8 a = *(const bf16x8*)&sh_H[hb][mj * 16 + c16][kt * 32 + q4 * 8];
                    acc2[mj] = __builtin_amdgcn_mfma_f32_16x16x32_bf16(a, b, acc2[mj], 0, 0, 0);
                }
            }
            const int rcol = wv * 16 + c16;
            #pragma unroll
            for (int mj = 0; mj < 4; ++mj)
                #pragma unroll
                for (int rr = 0; rr < 4; ++rr)
                    sh_S[mj * 16 + q4 * 4 + rr][rcol] = f2bf(acc2[mj][rr]);
        }
        __syncthreads();

        // ==== R2: C2 (MFMA): at = relu(P @ S + soc_b) over k'=(j,g) ====
        {
            const int mt = wv & 3, nt = wv >> 2;
            const int cb = 4 * (nt * 16 + c16);
            f32x4 cac = (f32x4){0.f, 0.f, 0.f, 0.f};
            #pragma unroll
            for (int kt = 0; kt < 8; ++kt) {
                const bf16x8 a = *(const bf16x8*)&sh_P[mt * 16 + c16][kt * 32 + q4 * 8];
                const int j0 = kt * 8 + q4 * 2;
                const bf16x4 lo = *(const bf16x4*)&sh_S[j0][cb];
                const bf16x4 hi = *(const bf16x4*)&sh_S[j0 + 1][cb];
                const bf16x8 b = __builtin_shufflevector(lo, hi, 0, 1, 2, 3, 4, 5, 6, 7);
                cac = __builtin_amdgcn_mfma_f32_16x16x32_bf16(a, b, cac, 0, 0, 0);
            }
            const int e = nt * 16 + c16;
            const float sb = soc_b[e];
            #pragma unroll
            for (int rr = 0; rr < 4; ++rr)
                sh_X[mt * 16 + q4 * 4 + rr][64 + e] = f2bf(fmaxf(cac[rr] + sb, 0.f));
        }
        __syncthreads();

        // ==== R3: D (MFMA) + shfl pointwise; h' -> opposite parity via h_rg ====
        {
            f32x4 acc[4][2];
            #pragma unroll
            for (int mj = 0; mj < 4; ++mj) {
                acc[mj][0] = (f32x4){0.f, 0.f, 0.f, 0.f};
                acc[mj][1] = (f32x4){0.f, 0.f, 0.f, 0.f};
            }
            #pragma unroll 2
            for (int kt = 0; kt < 8; ++kt) {
                const bf16x8 b0 = wdp[kt * 64];
                const bf16x8 b1 = wdp[kt * 64 + 512];
                #pragma unroll
                for (int mj = 0; mj < 4; ++mj) {
                    const bf16x8 a = (kt < 4)
                        ? *(const bf16x8*)&sh_X[mj * 16 + c16][kt * 32 + q4 * 8]
                        : *(const bf16x8*)&sh_H[hb][mj * 16 + c16][(kt - 4) * 32 + q4 * 8];
                    acc[mj][0] = __builtin_amdgcn_mfma_f32_16x16x32_bf16(a, b0, acc[mj][0], 0, 0, 0);
                    acc[mj][1] = __builtin_amdgcn_mfma_f32_16x16x32_bf16(a, b1, acc[mj][1], 0, 0, 0);
                }
            }
            // pointwise LSTM: 4-lane gate exchange; hold in h_rg, write h' to sh_H[hb^1]
            #pragma unroll
            for (int mj = 0; mj < 4; ++mj) {
                const int a = mj * 16 + q4 * 4 + go;
                const bool act = sh_act[ab][a] != 0;
                #pragma unroll
                for (int s = 0; s < 2; ++s) {
                    const float z0 = acc[mj][s][0] + bs[s];
                    const float z1 = acc[mj][s][1] + bs[s];
                    const float z2 = acc[mj][s][2] + bs[s];
                    const float z3 = acc[mj][s][3] + bs[s];
                    const float s0 = sel4(z0, z1, z2, z3, go);
                    const float s1 = sel4(z0, z1, z2, z3, go ^ 1);
                    const float s2 = sel4(z0, z1, z2, z3, go ^ 2);
                    const float s3 = sel4(z0, z1, z2, z3, go ^ 3);
                    const float t1 = __shfl_xor(s1, 1, 64);
                    const float t2 = __shfl_xor(s2, 2, 64);
                    const float t3 = __shfl_xor(s3, 3, 64);
                    const float zi = sel4(s0, t1, t2, t3, go);
                    const float zf = sel4(s0, t1, t2, t3, go ^ 1);
                    const float zg = sel4(s0, t1, t2, t3, go ^ 2);
                    const float zo = sel4(s0, t1, t2, t3, go ^ 3);
                    const float cold = c_st[mj][s];
                    const float cn = sigmf(zf) * cold + sigmf(zi) * tanhf_fast(zg);
                    const float hn = sigmf(zo) * tanhf_fast(cn);
                    c_st[mj][s] = act ? cn : cold;
                    h_rg[mj][s] = act ? hn : h_rg[mj][s];
                    sh_H[hb ^ 1][a][dimv[s]] = f2bf(h_rg[mj][s]);
                }
            }
        }
        // obs prefetch for step+1 into the idle parity
        if (step + 1 < TOBS && tid < NAGENT) {
            const int ig = gbase + tid;
            const int np = (step + 1) & 1;
            sh_px[np][tid] = past_traj[(ig * TOBS + step + 1) * 2 + 0];
            sh_py[np][tid] = past_traj[(ig * TOBS + step + 1) * 2 + 1];
            sh_rx[np][tid] = past_traj_rel[(ig * TOBS + step + 1) * 2 + 0];
            sh_ry[np][tid] = past_traj_rel[(ig * TOBS + step + 1) * 2 + 1];
            sh_act[np][tid] = (ts_mask[ig * TOBS + step + 1] == 1) ? 1 : 0;
        }
        __syncthreads();   // end of step
    }
}

extern "C" void kernel_launch(void* const* d_in, const int* in_sizes, int n_in,
                              void* d_out, int out_size, void* d_ws, size_t ws_size,
                              hipStream_t stream) {
    (void)in_sizes; (void)n_in; (void)out_size; (void)ws_size;
    unsigned short* wd = (unsigned short*)d_ws;            // 131072 ushorts
    unsigned short* wb = wd + 131072;                      //  32768 ushorts
    unsigned short* wp = wb + 32768;                       //   4096 ushorts
    prep_weights<<<656, 256, 0, stream>>>(
        (const float*)d_in[9], (const float*)d_in[10],
        (const float*)d_in[7], (const float*)d_in[15], wd, wb, wp);
    social_lstm_mfma<<<16, NTHR, 0, stream>>>(
        (const float*)d_in[0],   // past_traj
        (const float*)d_in[1],   // past_traj_rel
        (const int*)  d_in[2],   // ts mask
        (const int*)  d_in[4],   // same_scene_mask
        (const float*)d_in[5],   // pos_W
        (const float*)d_in[6],   // pos_b
        (const float*)d_in[8],   // soc_b
        (const float*)d_in[11],  // bih
        (const float*)d_in[12],  // bhh
        (const float*)d_in[13],  // h0
        (const float*)d_in[14],  // c0
        (const float*)d_in[16],  // pred_b
        wd, wb, wp,
        (float*)d_out);
}